// Round 3
// baseline (249.221 us; speedup 1.0000x reference)
//
#include <hip/hip_runtime.h>
#include <math.h>

// ---- Problem constants -----------------------------------------------------
#define NQ        12
#define NPS       14
#define NPATCH    196
#define NB        4
#define NCLS      1000
#define FEATDIM   2352           // 196*12
#define SCALE_F   0.28867513459481287f  // 1/sqrt(12)

typedef float v2f __attribute__((ext_vector_type(2)));

// ---- Persistent device-global scratch (replaces d_ws; poison-immune) --------
__device__ float    g_qkv[3 * NB * NPATCH * NQ];   // (3,784,12)
__device__ float    g_outb[NB * FEATDIM];          // (4,2352)
__device__ unsigned g_sync;     // monotonic attn-done counter (NEVER reset)
__device__ unsigned g_target;   // set by qcirc each replay: g_sync + 784

// ---- Layouts (identical to verified round-8/9 kernels) ----------------------
// 128-thread block (2 waves), 32 amps/thread. Frozen: q2 at amp bit0 (w=1),
// q3 at amp bit1 (w=2) in EVERY layout -> relayout reads are 4-word contiguous
// (b128) AND most gates act identically on the q2-pair -> packed v_pk_*_f32.
constexpr int PRa[8][5] = {
    {2,3,0,1, 4},   // S1 trio q0,q1,q4
    {2,3,4,5, 6},   // S2 trio q4,q5,q6
    {2,3,5,6, 7},   // S3 trio q5,q6,q7
    {2,3,0,4, 6},   // S4 trio q0,q4,q6
    {2,3,8,9,10},   // S5 trio q8,q9,q10
    {2,3,9,10,11},  // S6 trio q9,q10,q11
    {2,3,0,8,10},   // S7 trio q0,q8,q10
    {2,3,1,5, 9},   // S8 trio q1,q5,q9
};
constexpr int PTa[8][7] = {
    {5,6,7,8,9,10,11},   // S1 | wave q11
    {7,0,1,8,9,10,11},   // S2 | wave q11
    {0,1,4,8,9,10,11},   // S3 | wave q11
    {8,9,10,1,5,7,11},   // S4 | wave q11
    {4,0,1,5,6,7,11},    // S5 | wave q11
    {0,1,8,5,6,7,4},     // S6 | wave q4
    {1,5,9,6,7,11,4},    // S7 | wave q4
    {6,0,11,7,8,10,4},   // S8 | wave q4
};
constexpr bool BARa[8] = {false,false,false,false,true,false,false,true};

// ---- Two-pass half-buffer relayout (verified round 2) ------------------------
// 16 floats/thread LDS buffer; split by source amp bit 16 = qubit H=PRa[X][4].
// Pass 0 stages amps 0..15, pass 1 stages 16..31 in the same buffer.
// Register discipline: dest slots 0..7 commit immediately after R0 (old regs
// dead after W0); only quads destined for amp2[8..15] are held across W1.
constexpr int STRIDE = 20;

constexpr int cwgt2(int X, int q) {
    for (int k = 0; k < 4; ++k) if (PRa[X][k] == q) return 1 << k;   // reg bits
    if (PRa[X][4] == q) return 0;                                    // split bit
    for (int m = 0; m < 7; ++m) if (PTa[X][m] == q) return STRIDE << m;
    return 0;
}
constexpr int rimm2(int X, int Y, int a) {
    int s = 0;
    for (int j = 0; j < 3; ++j)
        if ((a >> j) & 1) s += cwgt2(X, PRa[Y][2 + j]);
    return s;
}
constexpr int splitpos(int X) {
    int Y = (X + 1) & 7, H = PRa[X][4];
    for (int j = 0; j < 3; ++j) if (PRa[Y][2 + j] == H) return j;
    for (int m = 0; m < 7; ++m) if (PTa[Y][m] == H) return 8 + m;
    return -1;
}

// Intra-wave relayouts (BAR=false): LDS processes a wave's DS ops in program
// order -> no explicit sync. Cross-wave (BAR=true): 4 barriers.
template<int TI>
__device__ __forceinline__ void relayout2(v2f amp2[16], float* lds, int tid, int base) {
    constexpr int X = TI, Y = (TI + 1) & 7;
    constexpr int SP = splitpos(TI);
    constexpr bool BAR = BARa[TI];
    float4* dst = (float4*)(lds + STRIDE * tid);

    // W0: stage source amps 0..15
    #pragma unroll
    for (int k = 0; k < 4; ++k)
        dst[k] = make_float4(amp2[2*k][0], amp2[2*k][1], amp2[2*k+1][0], amp2[2*k+1][1]);
    if (BAR) __syncthreads();

    float4 rvh[4];

    if constexpr (SP < 3) {
        #pragma unroll
        for (int a = 0; a < 8; ++a) {
            if ((a >> SP) & 1) continue;
            float4 v = *(const float4*)(lds + base + rimm2(X, Y, a));
            if (a < 4) {
                amp2[2*a][0]   = v.x; amp2[2*a][1]   = v.y;
                amp2[2*a+1][0] = v.z; amp2[2*a+1][1] = v.w;
            } else {
                rvh[a-4] = v;
            }
        }
        if (BAR) __syncthreads();
        #pragma unroll
        for (int k = 0; k < 4; ++k)
            dst[k] = make_float4(amp2[8+2*k][0], amp2[8+2*k][1], amp2[9+2*k][0], amp2[9+2*k][1]);
        #pragma unroll
        for (int a = 4; a < 8; ++a) {
            if ((a >> SP) & 1) continue;
            amp2[2*a][0]   = rvh[a-4].x; amp2[2*a][1]   = rvh[a-4].y;
            amp2[2*a+1][0] = rvh[a-4].z; amp2[2*a+1][1] = rvh[a-4].w;
        }
        if (BAR) __syncthreads();
        #pragma unroll
        for (int a = 0; a < 8; ++a) {
            if (!((a >> SP) & 1)) continue;
            float4 v = *(const float4*)(lds + base + rimm2(X, Y, a));
            amp2[2*a][0]   = v.x; amp2[2*a][1]   = v.y;
            amp2[2*a+1][0] = v.z; amp2[2*a+1][1] = v.w;
        }
        if (BAR) __syncthreads();
    } else {
        constexpr int TB = SP - 8;
        const bool p0 = ((tid >> TB) & 1) == 0;
        if (p0) {
            #pragma unroll
            for (int a = 0; a < 4; ++a) {
                float4 v = *(const float4*)(lds + base + rimm2(X, Y, a));
                amp2[2*a][0]   = v.x; amp2[2*a][1]   = v.y;
                amp2[2*a+1][0] = v.z; amp2[2*a+1][1] = v.w;
            }
            #pragma unroll
            for (int a = 4; a < 8; ++a)
                rvh[a-4] = *(const float4*)(lds + base + rimm2(X, Y, a));
        }
        if (BAR) __syncthreads();
        #pragma unroll
        for (int k = 0; k < 4; ++k)
            dst[k] = make_float4(amp2[8+2*k][0], amp2[8+2*k][1], amp2[9+2*k][0], amp2[9+2*k][1]);
        if (BAR) __syncthreads();
        if (p0) {
            #pragma unroll
            for (int a = 4; a < 8; ++a) {
                amp2[2*a][0]   = rvh[a-4].x; amp2[2*a][1]   = rvh[a-4].y;
                amp2[2*a+1][0] = rvh[a-4].z; amp2[2*a+1][1] = rvh[a-4].w;
            }
        } else {
            #pragma unroll
            for (int a = 0; a < 8; ++a) {
                float4 v = *(const float4*)(lds + base + rimm2(X, Y, a));
                amp2[2*a][0]   = v.x; amp2[2*a][1]   = v.y;
                amp2[2*a+1][0] = v.z; amp2[2*a+1][1] = v.w;
            }
        }
        if (BAR) __syncthreads();
    }
}

// ---- Gates -------------------------------------------------------------------
// Packed RBS gate: masks MI,MJ in amp2-index space. Half-angle form:
// gc=0.5cos(2t), gs=0.5sin(2t). 12 pk-instr per 4 v2f.
template<int MI, int MJ>
__device__ __forceinline__ void pk_gate(v2f a[16], float gc, float gs) {
    v2f H = {0.5f, 0.5f}, C = {gc, gc}, S = {gs, gs};
    #pragma unroll
    for (int m = 0; m < 16; ++m) {
        if (m & (MI | MJ)) continue;
        v2f a0 = a[m], a1 = a[m | MJ], a2 = a[m | MI], a3 = a[m | MI | MJ];
        v2f p  = a0 + a1, q  = a0 - a1;
        v2f p2 = a2 + a3, q2 = a2 - a3;
        v2f t1 = H * p  + C * q  - S * q2;
        v2f t2 = H * p2 + C * q2 + S * q;
        a[m]           = t1;
        a[m | MJ]      = p  - t1;
        a[m | MI]      = t2;
        a[m | MI | MJ] = p2 - t2;
    }
}

// Gate with MI=1 (q2, the packed-pair bit) and MJ=2*MJ2>=2, fully packed:
// A=(a0,a2)=v2f[i], B=(a1,a3)=v2f[i|MJ2]; P=A+B=(p,p2), Q=A-B=(q,q2);
// T=(t1,t2)=H*P+C*Q+(-gs,+gs)*swap(Q); A'=T, B'=P-T.   6 pk-instr per 4 amps.
// (Algebra checked term-by-term against the scalar sc_gate reference.)
template<int MJ2>
__device__ __forceinline__ void pq1_gate(v2f a[16], float gc, float gs) {
    v2f H = {0.5f, 0.5f}, C = {gc, gc}, S2 = {-gs, gs};
    #pragma unroll
    for (int i = 0; i < 16; ++i) {
        if (i & MJ2) continue;
        v2f A = a[i], B = a[i | MJ2];
        v2f P = A + B, Q = A - B;
        v2f Qs = __builtin_shufflevector(Q, Q, 1, 0);
        v2f T = H * P + C * Q + S2 * Qs;
        a[i]       = T;
        a[i | MJ2] = P - T;
    }
}

// Gate with MJ=1 (q2) and MI=2*MI2>=2, horizontal packed form:
// A=(a0,a1)=v2f[i], D=(a2,a3)=v2f[i|MI2]; X=A+swap(A)=(p,p), Y=A-swap(A)=(q,-q),
// likewise X2,Y2; A'=(t1,p-t1)=H*X+C*Y-gs*Y2; D'=(t2,p2-t2)=H*X2+C*Y2+gs*Y.
template<int MI2>
__device__ __forceinline__ void pq6_gate(v2f a[16], float gc, float gs) {
    v2f H = {0.5f, 0.5f}, C = {gc, gc}, Sp = {gs, gs}, Sn = {-gs, -gs};
    #pragma unroll
    for (int i = 0; i < 16; ++i) {
        if (i & MI2) continue;
        v2f A = a[i], D = a[i | MI2];
        v2f As = __builtin_shufflevector(A, A, 1, 0);
        v2f Ds = __builtin_shufflevector(D, D, 1, 0);
        v2f X  = A + As, Y  = A - As;
        v2f X2 = D + Ds, Y2 = D - Ds;
        a[i]       = H * X  + C * Y  + Sn * Y2;
        a[i | MI2] = H * X2 + C * Y2 + Sp * Y;
    }
}

// ---- DPP wave-wide sum (result valid in lane 63), pure VALU ----------------
template<int CTRL>
__device__ __forceinline__ float dppadd(float x) {
    int s = __builtin_amdgcn_update_dpp(0, __float_as_int(x), CTRL, 0xf, 0xf, true);
    return x + __int_as_float(s);
}
__device__ __forceinline__ float wave_sum(float x) {
    x = dppadd<0x111>(x);   // row_shr:1
    x = dppadd<0x112>(x);   // row_shr:2
    x = dppadd<0x114>(x);   // row_shr:4
    x = dppadd<0x118>(x);   // row_shr:8
    x = dppadd<0x142>(x);   // row_bcast:15
    x = dppadd<0x143>(x);   // row_bcast:31
    return x;
}

// ---- Kernel: fused projection + quantum circuit ----------------------------
// grid (196, 4, 3), block 128 (two waves). LDS ~10.75 KB, VGPR cap 96.
__global__ __launch_bounds__(128, 5) void qcirc_kernel(
    const float* __restrict__ x,      // (4,3,224,224)
    const float* __restrict__ Wp,     // (12,256)
    const float* __restrict__ bproj,  // (12,)
    const float* __restrict__ qp,
    const float* __restrict__ kp,
    const float* __restrict__ vp)
{
    __shared__ __align__(16) float lds[STRIDE * 128];
    __shared__ float chs[NQ], shs[NQ];
    __shared__ float gC[40], gS[40];
    __shared__ float red2[2][12];

    const int tid = threadIdx.x;
    const int p = blockIdx.x, b = blockIdx.y, c = blockIdx.z;
    const int bp = b * NPATCH + p;
    const float* params = (c == 0) ? qp : (c == 1) ? kp : vp;
    const int lane = tid & 63, wv = tid >> 6;

    // Per-replay sync target for the fused attn+cls kernel. g_sync is stable
    // during this kernel (only the previous replay's attn modified it, and
    // that dispatch completed before this one started on the same stream).
    if (p == 0 && b == 0 && c == 0 && tid == 0)
        g_target = __hip_atomic_load(&g_sync, __ATOMIC_RELAXED,
                                     __HIP_MEMORY_SCOPE_AGENT) + (unsigned)NB * NPATCH;

    // ---- projection: 2 pixels/thread, DPP wave sums ----
    float part[NQ];
    #pragma unroll
    for (int q = 0; q < NQ; ++q) part[q] = 0.0f;
    {
        int py = p / NPS, px = p % NPS;
        const float* xb = x + (size_t)b * 3 * 224 * 224;
        #pragma unroll
        for (int k = 0; k < 2; ++k) {
            int pix = tid + 128 * k;
            int off = (py * 16 + (pix >> 4)) * 224 + px * 16 + (pix & 15);
            float v = (xb[off] + xb[off + 50176] + xb[off + 100352]) * (1.0f / 3.0f);
            #pragma unroll
            for (int q = 0; q < NQ; ++q) part[q] += v * Wp[q * 256 + pix];
        }
    }
    if (tid < 40) {
        int l = tid / 20, g = tid - l * 20;
        float th = params[l * 32 + g];
        gC[tid] = 0.5f * cosf(2.0f * th);
        gS[tid] = 0.5f * sinf(2.0f * th);
    }
    #pragma unroll
    for (int q = 0; q < NQ; ++q) part[q] = wave_sum(part[q]);
    if (lane == 63) {
        #pragma unroll
        for (int q = 0; q < NQ; ++q) red2[wv][q] = part[q];
    }
    __syncthreads();
    if (tid < NQ) {
        float h = 0.5f * (red2[0][tid] + red2[1][tid] + bproj[tid]);
        chs[tid] = cosf(h); shs[tid] = sinf(h);
    }
    __syncthreads();

    // ---- relayout read bases (8 transitions, reused both layers) ----
    int baseT[8];
    #pragma unroll
    for (int TI = 0; TI < 8; ++TI) {
        int Y = (TI + 1) & 7, s = 0;
        #pragma unroll
        for (int j = 0; j < 7; ++j)
            s += ((tid >> j) & 1) ? cwgt2(TI, PTa[Y][j]) : 0;
        baseT[TI] = s;
    }

    // ---- init in S1: amp b0=q2 b1=q3 b2=q0 b3=q1 b4=q4;
    //      tid t0=q5 t1=q6 t2=q7 t3=q8 t4=q9 t5=q10 | wave t6=q11 ----
    v2f amp2[16];
    float* amp = (float*)amp2;
    {
        float hi = ((tid &  1) ? shs[5]  : chs[5])  *
                   ((tid &  2) ? shs[6]  : chs[6])  *
                   ((tid &  4) ? shs[7]  : chs[7])  *
                   ((tid &  8) ? shs[8]  : chs[8])  *
                   ((tid & 16) ? shs[9]  : chs[9])  *
                   ((tid & 32) ? shs[10] : chs[10]) *
                   ((tid & 64) ? shs[11] : chs[11]);
        float pA[8], pB[4];
        #pragma unroll
        for (int i = 0; i < 8; ++i)
            pA[i] = ((i & 1) ? shs[2] : chs[2]) * ((i & 2) ? shs[3] : chs[3]) *
                    ((i & 4) ? shs[0] : chs[0]);
        #pragma unroll
        for (int i = 0; i < 4; ++i)
            pB[i] = ((i & 1) ? shs[1] : chs[1]) * ((i & 2) ? shs[4] : chs[4]);
        #pragma unroll
        for (int r = 0; r < 32; ++r) amp[r] = pA[r & 7] * pB[r >> 3] * hi;
    }

    // ---- 2 layers x 8 runs; 15 relayouts; schedule identical to verified r8/r9.
    //      Gates touching q2 (mask bit0) now packed:
    //      p1=sc<1,2> -> pq1<1>; p6=sc<4,1> -> pq6<2>; p14,p18=sc<1,16> -> pq1<8>.
    #pragma unroll 1
    for (int l = 0; l < 2; ++l) {
        const int bb = l * 20;
        // S1 trio(q0,q1,q4): p0(0,1) p1(2,3) p6(0,2) p7(1,3)
        pk_gate<2, 4>(amp2, gC[bb+0], gS[bb+0]);
        pq1_gate<1>(amp2,   gC[bb+1], gS[bb+1]);
        pq6_gate<2>(amp2,   gC[bb+6], gS[bb+6]);
        pk_gate<4, 1>(amp2, gC[bb+7], gS[bb+7]);
        relayout2<0>(amp2, lds, tid, baseT[0]);
        // S2 trio(q4,q5,q6): p2(4,5)
        pk_gate<2, 4>(amp2, gC[bb+2], gS[bb+2]);
        relayout2<1>(amp2, lds, tid, baseT[1]);
        // S3 trio(q5,q6,q7): p3(6,7) p9(5,7) p15(3,7)
        pk_gate<4, 8>(amp2, gC[bb+3],  gS[bb+3]);
        pk_gate<2, 8>(amp2, gC[bb+9],  gS[bb+9]);
        pk_gate<1, 8>(amp2, gC[bb+15], gS[bb+15]);
        relayout2<2>(amp2, lds, tid, baseT[2]);
        // S4 trio(q0,q4,q6): p8(4,6) p12(0,4) p14(2,6)
        pk_gate<4, 8>(amp2, gC[bb+8],  gS[bb+8]);
        pk_gate<2, 4>(amp2, gC[bb+12], gS[bb+12]);
        pq1_gate<8>(amp2,   gC[bb+14], gS[bb+14]);
        relayout2<3>(amp2, lds, tid, baseT[3]);
        // S5 trio(q8,q9,q10): p4(8,9)
        pk_gate<2, 4>(amp2, gC[bb+4], gS[bb+4]);
        relayout2<4>(amp2, lds, tid, baseT[4]);
        // S6 trio(q9,q10,q11): p5(10,11) p11(9,11) p19(3,11)
        pk_gate<4, 8>(amp2, gC[bb+5],  gS[bb+5]);
        pk_gate<2, 8>(amp2, gC[bb+11], gS[bb+11]);
        pk_gate<1, 8>(amp2, gC[bb+19], gS[bb+19]);
        relayout2<5>(amp2, lds, tid, baseT[5]);
        // S7 trio(q0,q8,q10): p10(8,10) p16(0,8) p18(2,10)
        pk_gate<4, 8>(amp2, gC[bb+10], gS[bb+10]);
        pk_gate<2, 4>(amp2, gC[bb+16], gS[bb+16]);
        pq1_gate<8>(amp2,   gC[bb+18], gS[bb+18]);
        relayout2<6>(amp2, lds, tid, baseT[6]);
        // S8 trio(q1,q5,q9): p13(1,5) p17(1,9)
        pk_gate<2, 4>(amp2, gC[bb+13], gS[bb+13]);
        pk_gate<2, 8>(amp2, gC[bb+17], gS[bb+17]);
        if (l == 0) relayout2<7>(amp2, lds, tid, baseT[7]);
    }

    // ---- expvals in S8: amp b0=q2 b1=q3 b2=q1 b3=q5 b4=q9;
    //      tid t0=q6 t1=q0 t2=q11 t3=q7 t4=q8 t5=q10 | wave t6=q4 ----
    float T, Sq2, Sq3, Sq1, Sq5, Sq9;
    {
        float t1[16]; Sq2 = 0.0f;
        #pragma unroll
        for (int i = 0; i < 16; ++i) {
            float e = amp[2*i] * amp[2*i], o = amp[2*i+1] * amp[2*i+1];
            t1[i] = e + o; Sq2 += e - o;
        }
        float t2[8]; Sq3 = 0.0f;
        #pragma unroll
        for (int i = 0; i < 8; ++i) { t2[i] = t1[2*i] + t1[2*i+1]; Sq3 += t1[2*i] - t1[2*i+1]; }
        float t3[4]; Sq1 = 0.0f;
        #pragma unroll
        for (int i = 0; i < 4; ++i) { t3[i] = t2[2*i] + t2[2*i+1]; Sq1 += t2[2*i] - t2[2*i+1]; }
        float t4[2]; Sq5 = 0.0f;
        #pragma unroll
        for (int i = 0; i < 2; ++i) { t4[i] = t3[2*i] + t3[2*i+1]; Sq5 += t3[2*i] - t3[2*i+1]; }
        T = t4[0] + t4[1]; Sq9 = t4[0] - t4[1];
    }
    float Vq6  = (tid &  1) ? -T : T;
    float Vq0  = (tid &  2) ? -T : T;
    float Vq11 = (tid &  4) ? -T : T;
    float Vq7  = (tid &  8) ? -T : T;
    float Vq8  = (tid & 16) ? -T : T;
    float Vq10 = (tid & 32) ? -T : T;
    T    = wave_sum(T);
    Vq6  = wave_sum(Vq6);  Vq0  = wave_sum(Vq0);  Vq11 = wave_sum(Vq11);
    Vq7  = wave_sum(Vq7);  Vq8  = wave_sum(Vq8);  Vq10 = wave_sum(Vq10);
    Sq2  = wave_sum(Sq2);  Sq3  = wave_sum(Sq3);  Sq1  = wave_sum(Sq1);
    Sq5  = wave_sum(Sq5);  Sq9  = wave_sum(Sq9);
    if (lane == 63) {
        red2[wv][0]  = Vq0;  red2[wv][1]  = Sq1;  red2[wv][2]  = Sq2;
        red2[wv][3]  = Sq3;  red2[wv][4]  = T;    red2[wv][5]  = Sq5;
        red2[wv][6]  = Vq6;  red2[wv][7]  = Vq7;  red2[wv][8]  = Vq8;
        red2[wv][9]  = Sq9;  red2[wv][10] = Vq10; red2[wv][11] = Vq11;
    }
    __syncthreads();
    if (tid < NQ) {
        float v1 = red2[1][tid];
        float s = red2[0][tid] + ((tid == 4) ? -v1 : v1);   // wave bit = q4
        g_qkv[((size_t)c * (NB * NPATCH) + bp) * NQ + tid] = s;
    }
}

// ---- Kernel: fused attention + classifier -----------------------------------
// grid 1000 blocks x 256 threads. Blocks 0..783 compute one attn row, then ALL
// blocks sync on the monotonic counter and compute one classifier output each.
// Deadlock-impossible: 1000 blocks x 4 waves all co-resident (capacity >=1024
// blocks even at 4 blocks/CU). Replay-safe: a standalone re-dispatch (rocprof
// counter pass) only over-satisfies g_sync >= g_target, never hangs.
__global__ __launch_bounds__(256) void attncls_kernel(
    const float* __restrict__ Wc,     // (1000,2352)
    const float* __restrict__ bc,     // (1000,)
    float* __restrict__ logits)       // (4,1000)
{
    int bid = blockIdx.x, tid = threadIdx.x;
    int lane = tid & 63, wv = tid >> 6;
    const float* Q = g_qkv;
    const float* K = g_qkv + NB * NPATCH * NQ;
    const float* V = g_qkv + 2 * NB * NPATCH * NQ;

    __shared__ float redm[4], reds[4], redv[4][NQ];

    if (bid < NB * NPATCH) {
        int b = bid / NPATCH, qp = bid - b * NPATCH;

        float4 q0 = ((const float4*)(Q + (b * NPATCH + qp) * NQ))[0];
        float4 q1 = ((const float4*)(Q + (b * NPATCH + qp) * NQ))[1];
        float4 q2 = ((const float4*)(Q + (b * NPATCH + qp) * NQ))[2];

        float score = -1e30f;
        float4 v0, v1, v2;
        if (tid < NPATCH) {
            const float4* K4 = (const float4*)(K + (b * NPATCH + tid) * NQ);
            float4 k0 = K4[0], k1 = K4[1], k2 = K4[2];
            float s = q0.x*k0.x + q0.y*k0.y + q0.z*k0.z + q0.w*k0.w
                    + q1.x*k1.x + q1.y*k1.y + q1.z*k1.z + q1.w*k1.w
                    + q2.x*k2.x + q2.y*k2.y + q2.z*k2.z + q2.w*k2.w;
            score = s * SCALE_F;
            const float4* V4 = (const float4*)(V + (b * NPATCH + tid) * NQ);
            v0 = V4[0]; v1 = V4[1]; v2 = V4[2];
        }
        float m = score;
        #pragma unroll
        for (int o = 32; o > 0; o >>= 1) m = fmaxf(m, __shfl_down(m, o));
        if (lane == 0) redm[wv] = m;
        __syncthreads();
        float maxv = fmaxf(fmaxf(redm[0], redm[1]), fmaxf(redm[2], redm[3]));

        float w = (tid < NPATCH) ? expf(score - maxv) : 0.0f;
        float sm = w;
        #pragma unroll
        for (int o = 32; o > 0; o >>= 1) sm += __shfl_down(sm, o);
        if (lane == 0) reds[wv] = sm;

        float part[NQ];
        #pragma unroll
        for (int d = 0; d < NQ; d++) part[d] = 0.0f;
        if (tid < NPATCH) {
            part[0] = w*v0.x; part[1] = w*v0.y; part[2]  = w*v0.z; part[3]  = w*v0.w;
            part[4] = w*v1.x; part[5] = w*v1.y; part[6]  = w*v1.z; part[7]  = w*v1.w;
            part[8] = w*v2.x; part[9] = w*v2.y; part[10] = w*v2.z; part[11] = w*v2.w;
        }
        #pragma unroll
        for (int d = 0; d < NQ; d++) {
            #pragma unroll
            for (int o = 32; o > 0; o >>= 1) part[d] += __shfl_down(part[d], o);
        }
        if (lane == 0) {
            #pragma unroll
            for (int d = 0; d < NQ; d++) redv[wv][d] = part[d];
        }
        __syncthreads();
        if (tid < NQ) {
            float sumv = reds[0] + reds[1] + reds[2] + reds[3];
            float s = redv[0][tid] + redv[1][tid] + redv[2][tid] + redv[3][tid];
            g_outb[(size_t)b * FEATDIM + qp * NQ + tid] = s / sumv;
        }
        __syncthreads();                     // all outb stores issued & drained
        if (tid == 0) {
            __threadfence();                 // agent-visible before the signal
            __hip_atomic_fetch_add(&g_sync, 1u, __ATOMIC_RELEASE,
                                   __HIP_MEMORY_SCOPE_AGENT);
        }
    }

    // ---- device-wide wait: all 784 attn rows of THIS replay done ----
    if (tid == 0) {
        unsigned tgt = g_target;             // written by preceding qcirc kernel
        while ((int)(tgt - __hip_atomic_load(&g_sync, __ATOMIC_ACQUIRE,
                                             __HIP_MEMORY_SCOPE_AGENT)) > 0)
            __builtin_amdgcn_s_sleep(32);
    }
    __syncthreads();
    __threadfence();                         // invalidate caches: fresh outb

    // ---- classifier: one output column per block ----
    int o = bid;
    float acc[NB] = {0.0f, 0.0f, 0.0f, 0.0f};
    const float4* w4 = (const float4*)(Wc + (size_t)o * FEATDIM);
    for (int j = tid; j < FEATDIM / 4; j += 256) {
        float4 w = w4[j];
        #pragma unroll
        for (int b = 0; b < NB; b++) {
            float4 ov = ((const float4*)(g_outb + (size_t)b * FEATDIM))[j];
            acc[b] += w.x*ov.x + w.y*ov.y + w.z*ov.z + w.w*ov.w;
        }
    }
    #pragma unroll
    for (int b = 0; b < NB; b++) {
        #pragma unroll
        for (int off = 32; off > 0; off >>= 1) acc[b] += __shfl_down(acc[b], off);
    }
    __shared__ float red[4][NB];
    if (lane == 0) {
        #pragma unroll
        for (int b = 0; b < NB; b++) red[wv][b] = acc[b];
    }
    __syncthreads();
    if (tid < NB) {
        float s = red[0][tid] + red[1][tid] + red[2][tid] + red[3][tid];
        logits[(size_t)tid * NCLS + o] = s + bc[o];
    }
}

// ---- Launch ----------------------------------------------------------------
extern "C" void kernel_launch(void* const* d_in, const int* in_sizes, int n_in,
                              void* d_out, int out_size, void* d_ws, size_t ws_size,
                              hipStream_t stream) {
    const float* x     = (const float*)d_in[0];
    const float* Wp    = (const float*)d_in[1];
    const float* bproj = (const float*)d_in[2];
    const float* qp    = (const float*)d_in[3];
    const float* kp    = (const float*)d_in[4];
    const float* vp    = (const float*)d_in[5];
    const float* Wc    = (const float*)d_in[6];
    const float* bc    = (const float*)d_in[7];
    float* logits = (float*)d_out;
    (void)d_ws; (void)ws_size;

    qcirc_kernel  <<<dim3(NPATCH, NB, 3), 128, 0, stream>>>(x, Wp, bproj, qp, kp, vp);
    attncls_kernel<<<NCLS,                256, 0, stream>>>(Wc, bc, logits);
}

// Round 4
// 117.814 us; speedup vs baseline: 2.1154x; 2.1154x over previous
//
#include <hip/hip_runtime.h>
#include <math.h>

// ---- Problem constants -----------------------------------------------------
#define NQ        12
#define NPS       14
#define NPATCH    196
#define NB        4
#define NCLS      1000
#define FEATDIM   2352           // 196*12
#define SCALE_F   0.28867513459481287f  // 1/sqrt(12)

typedef float v2f __attribute__((ext_vector_type(2)));

// ---- Persistent device-global scratch (no d_ws dependency) ------------------
__device__ float g_qkv[3 * NB * NPATCH * NQ];   // (3,784,12)
__device__ float g_outb[NB * FEATDIM];          // (4,2352)

// ---- Layouts (identical to verified round-8/9 kernels) ----------------------
// 128-thread block (2 waves), 32 amps/thread. Frozen: q2 at amp bit0 (w=1),
// q3 at amp bit1 (w=2) in EVERY layout -> relayout reads are 4-word contiguous
// (b128) AND gates acting on the q2-pair pack onto v_pk_*_f32.
constexpr int PRa[8][5] = {
    {2,3,0,1, 4},   // S1 trio q0,q1,q4
    {2,3,4,5, 6},   // S2 trio q4,q5,q6
    {2,3,5,6, 7},   // S3 trio q5,q6,q7
    {2,3,0,4, 6},   // S4 trio q0,q4,q6
    {2,3,8,9,10},   // S5 trio q8,q9,q10
    {2,3,9,10,11},  // S6 trio q9,q10,q11
    {2,3,0,8,10},   // S7 trio q0,q8,q10
    {2,3,1,5, 9},   // S8 trio q1,q5,q9
};
constexpr int PTa[8][7] = {
    {5,6,7,8,9,10,11},   // S1 | wave q11
    {7,0,1,8,9,10,11},   // S2 | wave q11
    {0,1,4,8,9,10,11},   // S3 | wave q11
    {8,9,10,1,5,7,11},   // S4 | wave q11
    {4,0,1,5,6,7,11},    // S5 | wave q11
    {0,1,8,5,6,7,4},     // S6 | wave q4
    {1,5,9,6,7,11,4},    // S7 | wave q4
    {6,0,11,7,8,10,4},   // S8 | wave q4
};
constexpr bool BARa[8] = {false,false,false,false,true,false,false,true};

// ---- Two-pass half-buffer relayout (verified round 2) ------------------------
// 16 floats/thread LDS buffer; split by source amp bit 16 = qubit H=PRa[X][4].
// Pass 0 stages amps 0..15, pass 1 stages 16..31 in the same buffer.
// Register discipline (round-1 lesson: a 72-VGPR cap spilled the amp state to
// scratch at 42 MB/dispatch HBM): dest slots 0..7 commit immediately after R0
// (their old regs die at W0); only quads destined for amp2[8..15] are held
// across W1 (2 quads case A, 4 case B).
constexpr int STRIDE = 20;

constexpr int cwgt2(int X, int q) {
    for (int k = 0; k < 4; ++k) if (PRa[X][k] == q) return 1 << k;   // reg bits
    if (PRa[X][4] == q) return 0;                                    // split bit
    for (int m = 0; m < 7; ++m) if (PTa[X][m] == q) return STRIDE << m;
    return 0;
}
constexpr int rimm2(int X, int Y, int a) {
    int s = 0;
    for (int j = 0; j < 3; ++j)
        if ((a >> j) & 1) s += cwgt2(X, PRa[Y][2 + j]);
    return s;
}
constexpr int splitpos(int X) {
    int Y = (X + 1) & 7, H = PRa[X][4];
    for (int j = 0; j < 3; ++j) if (PRa[Y][2 + j] == H) return j;
    for (int m = 0; m < 7; ++m) if (PTa[Y][m] == H) return 8 + m;
    return -1;
}

// Intra-wave relayouts (BAR=false): LDS processes a wave's DS ops in program
// order -> no explicit sync (covers RAW and WAR of the two-pass scheme).
// Cross-wave (BAR=true): 4 barriers W0|bar|R0|bar|W1|bar|R1|bar.
template<int TI>
__device__ __forceinline__ void relayout2(v2f amp2[16], float* lds, int tid, int base) {
    constexpr int X = TI, Y = (TI + 1) & 7;
    constexpr int SP = splitpos(TI);
    constexpr bool BAR = BARa[TI];
    float4* dst = (float4*)(lds + STRIDE * tid);

    // W0: stage source amps 0..15
    #pragma unroll
    for (int k = 0; k < 4; ++k)
        dst[k] = make_float4(amp2[2*k][0], amp2[2*k][1], amp2[2*k+1][0], amp2[2*k+1][1]);
    if (BAR) __syncthreads();

    float4 rvh[4];

    if constexpr (SP < 3) {
        // case A: pass 0 serves destination a-values with bit SP == 0
        #pragma unroll
        for (int a = 0; a < 8; ++a) {
            if ((a >> SP) & 1) continue;
            float4 v = *(const float4*)(lds + base + rimm2(X, Y, a));
            if (a < 4) {
                amp2[2*a][0]   = v.x; amp2[2*a][1]   = v.y;
                amp2[2*a+1][0] = v.z; amp2[2*a+1][1] = v.w;
            } else {
                rvh[a-4] = v;
            }
        }
        if (BAR) __syncthreads();
        // W1: stage source amps 16..31 (old amp2[8..15])
        #pragma unroll
        for (int k = 0; k < 4; ++k)
            dst[k] = make_float4(amp2[8+2*k][0], amp2[8+2*k][1], amp2[9+2*k][0], amp2[9+2*k][1]);
        #pragma unroll
        for (int a = 4; a < 8; ++a) {
            if ((a >> SP) & 1) continue;
            amp2[2*a][0]   = rvh[a-4].x; amp2[2*a][1]   = rvh[a-4].y;
            amp2[2*a+1][0] = rvh[a-4].z; amp2[2*a+1][1] = rvh[a-4].w;
        }
        if (BAR) __syncthreads();
        // R1: dest a-values with bit SP == 1 (same addresses: split bit weight 0)
        #pragma unroll
        for (int a = 0; a < 8; ++a) {
            if (!((a >> SP) & 1)) continue;
            float4 v = *(const float4*)(lds + base + rimm2(X, Y, a));
            amp2[2*a][0]   = v.x; amp2[2*a][1]   = v.y;
            amp2[2*a+1][0] = v.z; amp2[2*a+1][1] = v.w;
        }
        if (BAR) __syncthreads();
    } else {
        // case B: dest tid bit TB selects the pass for ALL of this thread's reads
        constexpr int TB = SP - 8;
        const bool p0 = ((tid >> TB) & 1) == 0;
        if (p0) {
            #pragma unroll
            for (int a = 0; a < 4; ++a) {
                float4 v = *(const float4*)(lds + base + rimm2(X, Y, a));
                amp2[2*a][0]   = v.x; amp2[2*a][1]   = v.y;
                amp2[2*a+1][0] = v.z; amp2[2*a+1][1] = v.w;
            }
            #pragma unroll
            for (int a = 4; a < 8; ++a)
                rvh[a-4] = *(const float4*)(lds + base + rimm2(X, Y, a));
        }
        if (BAR) __syncthreads();
        #pragma unroll
        for (int k = 0; k < 4; ++k)
            dst[k] = make_float4(amp2[8+2*k][0], amp2[8+2*k][1], amp2[9+2*k][0], amp2[9+2*k][1]);
        if (BAR) __syncthreads();
        if (p0) {
            #pragma unroll
            for (int a = 4; a < 8; ++a) {
                amp2[2*a][0]   = rvh[a-4].x; amp2[2*a][1]   = rvh[a-4].y;
                amp2[2*a+1][0] = rvh[a-4].z; amp2[2*a+1][1] = rvh[a-4].w;
            }
        } else {
            #pragma unroll
            for (int a = 0; a < 8; ++a) {
                float4 v = *(const float4*)(lds + base + rimm2(X, Y, a));
                amp2[2*a][0]   = v.x; amp2[2*a][1]   = v.y;
                amp2[2*a+1][0] = v.z; amp2[2*a+1][1] = v.w;
            }
        }
        if (BAR) __syncthreads();
    }
}

// ---- Gates -------------------------------------------------------------------
// Packed RBS gate: masks MI,MJ in amp2-index space. Half-angle form:
// gc=0.5cos(2t), gs=0.5sin(2t).
template<int MI, int MJ>
__device__ __forceinline__ void pk_gate(v2f a[16], float gc, float gs) {
    v2f H = {0.5f, 0.5f}, C = {gc, gc}, S = {gs, gs};
    #pragma unroll
    for (int m = 0; m < 16; ++m) {
        if (m & (MI | MJ)) continue;
        v2f a0 = a[m], a1 = a[m | MJ], a2 = a[m | MI], a3 = a[m | MI | MJ];
        v2f p  = a0 + a1, q  = a0 - a1;
        v2f p2 = a2 + a3, q2 = a2 - a3;
        v2f t1 = H * p  + C * q  - S * q2;
        v2f t2 = H * p2 + C * q2 + S * q;
        a[m]           = t1;
        a[m | MJ]      = p  - t1;
        a[m | MI]      = t2;
        a[m | MI | MJ] = p2 - t2;
    }
}

// Gate with MI=1 (q2, the packed-pair bit) and MJ=2*MJ2>=2, fully packed:
// A=(a0,a2)=v2f[i], B=(a1,a3)=v2f[i|MJ2]; P=A+B=(p,p2), Q=A-B=(q,q2);
// T=(t1,t2)=H*P+C*Q+(-gs,+gs)*swap(Q); A'=T, B'=P-T.
// (Algebra verified term-by-term against the scalar reference; shipped and
// passing in round 3.)
template<int MJ2>
__device__ __forceinline__ void pq1_gate(v2f a[16], float gc, float gs) {
    v2f H = {0.5f, 0.5f}, C = {gc, gc}, S2 = {-gs, gs};
    #pragma unroll
    for (int i = 0; i < 16; ++i) {
        if (i & MJ2) continue;
        v2f A = a[i], B = a[i | MJ2];
        v2f P = A + B, Q = A - B;
        v2f Qs = __builtin_shufflevector(Q, Q, 1, 0);
        v2f T = H * P + C * Q + S2 * Qs;
        a[i]       = T;
        a[i | MJ2] = P - T;
    }
}

// Gate with MJ=1 (q2) and MI=2*MI2>=2, horizontal packed form:
// A=(a0,a1)=v2f[i], D=(a2,a3)=v2f[i|MI2]; X=A+swap(A), Y=A-swap(A);
// A'=(t1,p-t1)=H*X+C*Y-gs*Y2; D'=(t2,p2-t2)=H*X2+C*Y2+gs*Y.
template<int MI2>
__device__ __forceinline__ void pq6_gate(v2f a[16], float gc, float gs) {
    v2f H = {0.5f, 0.5f}, C = {gc, gc}, Sp = {gs, gs}, Sn = {-gs, -gs};
    #pragma unroll
    for (int i = 0; i < 16; ++i) {
        if (i & MI2) continue;
        v2f A = a[i], D = a[i | MI2];
        v2f As = __builtin_shufflevector(A, A, 1, 0);
        v2f Ds = __builtin_shufflevector(D, D, 1, 0);
        v2f X  = A + As, Y  = A - As;
        v2f X2 = D + Ds, Y2 = D - Ds;
        a[i]       = H * X  + C * Y  + Sn * Y2;
        a[i | MI2] = H * X2 + C * Y2 + Sp * Y;
    }
}

// ---- DPP wave-wide sum (result valid in lane 63), pure VALU ----------------
template<int CTRL>
__device__ __forceinline__ float dppadd(float x) {
    int s = __builtin_amdgcn_update_dpp(0, __float_as_int(x), CTRL, 0xf, 0xf, true);
    return x + __int_as_float(s);
}
__device__ __forceinline__ float wave_sum(float x) {
    x = dppadd<0x111>(x);   // row_shr:1
    x = dppadd<0x112>(x);   // row_shr:2
    x = dppadd<0x114>(x);   // row_shr:4
    x = dppadd<0x118>(x);   // row_shr:8
    x = dppadd<0x142>(x);   // row_bcast:15
    x = dppadd<0x143>(x);   // row_bcast:31
    return x;
}

// ---- Kernel: fused projection + quantum circuit ----------------------------
// grid (196, 4, 3), block 128 (two waves). LDS ~10.75 KB, VGPR cap 96
// ((128,5) — verified no-spill at VGPR=44 in round 2).
__global__ __launch_bounds__(128, 5) void qcirc_kernel(
    const float* __restrict__ x,      // (4,3,224,224)
    const float* __restrict__ Wp,     // (12,256)
    const float* __restrict__ bproj,  // (12,)
    const float* __restrict__ qp,
    const float* __restrict__ kp,
    const float* __restrict__ vp)
{
    __shared__ __align__(16) float lds[STRIDE * 128];
    __shared__ float chs[NQ], shs[NQ];
    __shared__ float gC[40], gS[40];
    __shared__ float red2[2][12];

    const int tid = threadIdx.x;
    const int p = blockIdx.x, b = blockIdx.y, c = blockIdx.z;
    const int bp = b * NPATCH + p;
    const float* params = (c == 0) ? qp : (c == 1) ? kp : vp;
    const int lane = tid & 63, wv = tid >> 6;

    // ---- projection: 2 pixels/thread, DPP wave sums ----
    float part[NQ];
    #pragma unroll
    for (int q = 0; q < NQ; ++q) part[q] = 0.0f;
    {
        int py = p / NPS, px = p % NPS;
        const float* xb = x + (size_t)b * 3 * 224 * 224;
        #pragma unroll
        for (int k = 0; k < 2; ++k) {
            int pix = tid + 128 * k;
            int off = (py * 16 + (pix >> 4)) * 224 + px * 16 + (pix & 15);
            float v = (xb[off] + xb[off + 50176] + xb[off + 100352]) * (1.0f / 3.0f);
            #pragma unroll
            for (int q = 0; q < NQ; ++q) part[q] += v * Wp[q * 256 + pix];
        }
    }
    if (tid < 40) {
        int l = tid / 20, g = tid - l * 20;
        float th = params[l * 32 + g];
        gC[tid] = 0.5f * cosf(2.0f * th);
        gS[tid] = 0.5f * sinf(2.0f * th);
    }
    #pragma unroll
    for (int q = 0; q < NQ; ++q) part[q] = wave_sum(part[q]);
    if (lane == 63) {
        #pragma unroll
        for (int q = 0; q < NQ; ++q) red2[wv][q] = part[q];
    }
    __syncthreads();
    if (tid < NQ) {
        float h = 0.5f * (red2[0][tid] + red2[1][tid] + bproj[tid]);
        chs[tid] = cosf(h); shs[tid] = sinf(h);
    }
    __syncthreads();

    // ---- relayout read bases (8 transitions, reused both layers) ----
    int baseT[8];
    #pragma unroll
    for (int TI = 0; TI < 8; ++TI) {
        int Y = (TI + 1) & 7, s = 0;
        #pragma unroll
        for (int j = 0; j < 7; ++j)
            s += ((tid >> j) & 1) ? cwgt2(TI, PTa[Y][j]) : 0;
        baseT[TI] = s;
    }

    // ---- init in S1: amp b0=q2 b1=q3 b2=q0 b3=q1 b4=q4;
    //      tid t0=q5 t1=q6 t2=q7 t3=q8 t4=q9 t5=q10 | wave t6=q11 ----
    v2f amp2[16];
    float* amp = (float*)amp2;
    {
        float hi = ((tid &  1) ? shs[5]  : chs[5])  *
                   ((tid &  2) ? shs[6]  : chs[6])  *
                   ((tid &  4) ? shs[7]  : chs[7])  *
                   ((tid &  8) ? shs[8]  : chs[8])  *
                   ((tid & 16) ? shs[9]  : chs[9])  *
                   ((tid & 32) ? shs[10] : chs[10]) *
                   ((tid & 64) ? shs[11] : chs[11]);
        float pA[8], pB[4];
        #pragma unroll
        for (int i = 0; i < 8; ++i)
            pA[i] = ((i & 1) ? shs[2] : chs[2]) * ((i & 2) ? shs[3] : chs[3]) *
                    ((i & 4) ? shs[0] : chs[0]);
        #pragma unroll
        for (int i = 0; i < 4; ++i)
            pB[i] = ((i & 1) ? shs[1] : chs[1]) * ((i & 2) ? shs[4] : chs[4]);
        #pragma unroll
        for (int r = 0; r < 32; ++r) amp[r] = pA[r & 7] * pB[r >> 3] * hi;
    }

    // ---- 2 layers x 8 runs; 15 relayouts; schedule identical to verified r8/r9.
    //      Gates touching q2 (mask bit0) packed:
    //      p1=sc<1,2> -> pq1<1>; p6=sc<4,1> -> pq6<2>; p14,p18=sc<1,16> -> pq1<8>.
    #pragma unroll 1
    for (int l = 0; l < 2; ++l) {
        const int bb = l * 20;
        // S1 trio(q0,q1,q4): p0(0,1) p1(2,3) p6(0,2) p7(1,3)
        pk_gate<2, 4>(amp2, gC[bb+0], gS[bb+0]);
        pq1_gate<1>(amp2,   gC[bb+1], gS[bb+1]);
        pq6_gate<2>(amp2,   gC[bb+6], gS[bb+6]);
        pk_gate<4, 1>(amp2, gC[bb+7], gS[bb+7]);
        relayout2<0>(amp2, lds, tid, baseT[0]);
        // S2 trio(q4,q5,q6): p2(4,5)
        pk_gate<2, 4>(amp2, gC[bb+2], gS[bb+2]);
        relayout2<1>(amp2, lds, tid, baseT[1]);
        // S3 trio(q5,q6,q7): p3(6,7) p9(5,7) p15(3,7)
        pk_gate<4, 8>(amp2, gC[bb+3],  gS[bb+3]);
        pk_gate<2, 8>(amp2, gC[bb+9],  gS[bb+9]);
        pk_gate<1, 8>(amp2, gC[bb+15], gS[bb+15]);
        relayout2<2>(amp2, lds, tid, baseT[2]);
        // S4 trio(q0,q4,q6): p8(4,6) p12(0,4) p14(2,6)
        pk_gate<4, 8>(amp2, gC[bb+8],  gS[bb+8]);
        pk_gate<2, 4>(amp2, gC[bb+12], gS[bb+12]);
        pq1_gate<8>(amp2,   gC[bb+14], gS[bb+14]);
        relayout2<3>(amp2, lds, tid, baseT[3]);
        // S5 trio(q8,q9,q10): p4(8,9)
        pk_gate<2, 4>(amp2, gC[bb+4], gS[bb+4]);
        relayout2<4>(amp2, lds, tid, baseT[4]);
        // S6 trio(q9,q10,q11): p5(10,11) p11(9,11) p19(3,11)
        pk_gate<4, 8>(amp2, gC[bb+5],  gS[bb+5]);
        pk_gate<2, 8>(amp2, gC[bb+11], gS[bb+11]);
        pk_gate<1, 8>(amp2, gC[bb+19], gS[bb+19]);
        relayout2<5>(amp2, lds, tid, baseT[5]);
        // S7 trio(q0,q8,q10): p10(8,10) p16(0,8) p18(2,10)
        pk_gate<4, 8>(amp2, gC[bb+10], gS[bb+10]);
        pk_gate<2, 4>(amp2, gC[bb+16], gS[bb+16]);
        pq1_gate<8>(amp2,   gC[bb+18], gS[bb+18]);
        relayout2<6>(amp2, lds, tid, baseT[6]);
        // S8 trio(q1,q5,q9): p13(1,5) p17(1,9)
        pk_gate<2, 4>(amp2, gC[bb+13], gS[bb+13]);
        pk_gate<2, 8>(amp2, gC[bb+17], gS[bb+17]);
        if (l == 0) relayout2<7>(amp2, lds, tid, baseT[7]);
    }

    // ---- expvals in S8: amp b0=q2 b1=q3 b2=q1 b3=q5 b4=q9;
    //      tid t0=q6 t1=q0 t2=q11 t3=q7 t4=q8 t5=q10 | wave t6=q4 ----
    float T, Sq2, Sq3, Sq1, Sq5, Sq9;
    {
        float t1[16]; Sq2 = 0.0f;
        #pragma unroll
        for (int i = 0; i < 16; ++i) {
            float e = amp[2*i] * amp[2*i], o = amp[2*i+1] * amp[2*i+1];
            t1[i] = e + o; Sq2 += e - o;
        }
        float t2[8]; Sq3 = 0.0f;
        #pragma unroll
        for (int i = 0; i < 8; ++i) { t2[i] = t1[2*i] + t1[2*i+1]; Sq3 += t1[2*i] - t1[2*i+1]; }
        float t3[4]; Sq1 = 0.0f;
        #pragma unroll
        for (int i = 0; i < 4; ++i) { t3[i] = t2[2*i] + t2[2*i+1]; Sq1 += t2[2*i] - t2[2*i+1]; }
        float t4[2]; Sq5 = 0.0f;
        #pragma unroll
        for (int i = 0; i < 2; ++i) { t4[i] = t3[2*i] + t3[2*i+1]; Sq5 += t3[2*i] - t3[2*i+1]; }
        T = t4[0] + t4[1]; Sq9 = t4[0] - t4[1];
    }
    float Vq6  = (tid &  1) ? -T : T;
    float Vq0  = (tid &  2) ? -T : T;
    float Vq11 = (tid &  4) ? -T : T;
    float Vq7  = (tid &  8) ? -T : T;
    float Vq8  = (tid & 16) ? -T : T;
    float Vq10 = (tid & 32) ? -T : T;
    T    = wave_sum(T);
    Vq6  = wave_sum(Vq6);  Vq0  = wave_sum(Vq0);  Vq11 = wave_sum(Vq11);
    Vq7  = wave_sum(Vq7);  Vq8  = wave_sum(Vq8);  Vq10 = wave_sum(Vq10);
    Sq2  = wave_sum(Sq2);  Sq3  = wave_sum(Sq3);  Sq1  = wave_sum(Sq1);
    Sq5  = wave_sum(Sq5);  Sq9  = wave_sum(Sq9);
    if (lane == 63) {
        red2[wv][0]  = Vq0;  red2[wv][1]  = Sq1;  red2[wv][2]  = Sq2;
        red2[wv][3]  = Sq3;  red2[wv][4]  = T;    red2[wv][5]  = Sq5;
        red2[wv][6]  = Vq6;  red2[wv][7]  = Vq7;  red2[wv][8]  = Vq8;
        red2[wv][9]  = Sq9;  red2[wv][10] = Vq10; red2[wv][11] = Vq11;
    }
    __syncthreads();
    if (tid < NQ) {
        float v1 = red2[1][tid];
        float s = red2[0][tid] + ((tid == 4) ? -v1 : v1);   // wave bit = q4
        g_qkv[((size_t)c * (NB * NPATCH) + bp) * NQ + tid] = s;
    }
}

// ---- Kernel: attention ------------------------------------------------------
__global__ __launch_bounds__(256) void attn_kernel(float* /*unused*/ )
{
    int tid = threadIdx.x;
    int qp = blockIdx.x, b = blockIdx.y;
    const float* Q = g_qkv;
    const float* K = g_qkv + NB * NPATCH * NQ;
    const float* V = g_qkv + 2 * NB * NPATCH * NQ;

    __shared__ float redm[4], reds[4], redv[4][NQ];

    float4 q0 = ((const float4*)(Q + (b * NPATCH + qp) * NQ))[0];
    float4 q1 = ((const float4*)(Q + (b * NPATCH + qp) * NQ))[1];
    float4 q2 = ((const float4*)(Q + (b * NPATCH + qp) * NQ))[2];

    float score = -1e30f;
    float4 v0, v1, v2;
    if (tid < NPATCH) {
        const float4* K4 = (const float4*)(K + (b * NPATCH + tid) * NQ);
        float4 k0 = K4[0], k1 = K4[1], k2 = K4[2];
        float s = q0.x*k0.x + q0.y*k0.y + q0.z*k0.z + q0.w*k0.w
                + q1.x*k1.x + q1.y*k1.y + q1.z*k1.z + q1.w*k1.w
                + q2.x*k2.x + q2.y*k2.y + q2.z*k2.z + q2.w*k2.w;
        score = s * SCALE_F;
        const float4* V4 = (const float4*)(V + (b * NPATCH + tid) * NQ);
        v0 = V4[0]; v1 = V4[1]; v2 = V4[2];
    }
    float m = score;
    #pragma unroll
    for (int o = 32; o > 0; o >>= 1) m = fmaxf(m, __shfl_down(m, o));
    int lane = tid & 63, wv = tid >> 6;
    if (lane == 0) redm[wv] = m;
    __syncthreads();
    float maxv = fmaxf(fmaxf(redm[0], redm[1]), fmaxf(redm[2], redm[3]));

    float w = (tid < NPATCH) ? expf(score - maxv) : 0.0f;
    float sm = w;
    #pragma unroll
    for (int o = 32; o > 0; o >>= 1) sm += __shfl_down(sm, o);
    if (lane == 0) reds[wv] = sm;

    float part[NQ];
    #pragma unroll
    for (int d = 0; d < NQ; d++) part[d] = 0.0f;
    if (tid < NPATCH) {
        part[0] = w*v0.x; part[1] = w*v0.y; part[2]  = w*v0.z; part[3]  = w*v0.w;
        part[4] = w*v1.x; part[5] = w*v1.y; part[6]  = w*v1.z; part[7]  = w*v1.w;
        part[8] = w*v2.x; part[9] = w*v2.y; part[10] = w*v2.z; part[11] = w*v2.w;
    }
    #pragma unroll
    for (int d = 0; d < NQ; d++) {
        #pragma unroll
        for (int o = 32; o > 0; o >>= 1) part[d] += __shfl_down(part[d], o);
    }
    if (lane == 0) {
        #pragma unroll
        for (int d = 0; d < NQ; d++) redv[wv][d] = part[d];
    }
    __syncthreads();
    if (tid < NQ) {
        float sumv = reds[0] + reds[1] + reds[2] + reds[3];
        float s = redv[0][tid] + redv[1][tid] + redv[2][tid] + redv[3][tid];
        g_outb[(size_t)b * FEATDIM + qp * NQ + tid] = s / sumv;
    }
}

// ---- Kernel: classifier -----------------------------------------------------
__global__ __launch_bounds__(256) void cls_kernel(
    const float* __restrict__ Wc,     // (1000,2352)
    const float* __restrict__ bc,     // (1000,)
    float* __restrict__ logits)       // (4,1000)
{
    int o = blockIdx.x, tid = threadIdx.x;
    float acc[NB] = {0.0f, 0.0f, 0.0f, 0.0f};
    const float4* w4 = (const float4*)(Wc + (size_t)o * FEATDIM);
    for (int j = tid; j < FEATDIM / 4; j += 256) {
        float4 w = w4[j];
        #pragma unroll
        for (int b = 0; b < NB; b++) {
            float4 ov = ((const float4*)(g_outb + (size_t)b * FEATDIM))[j];
            acc[b] += w.x*ov.x + w.y*ov.y + w.z*ov.z + w.w*ov.w;
        }
    }
    #pragma unroll
    for (int b = 0; b < NB; b++) {
        #pragma unroll
        for (int off = 32; off > 0; off >>= 1) acc[b] += __shfl_down(acc[b], off);
    }
    __shared__ float red[4][NB];
    int lane = tid & 63, wv = tid >> 6;
    if (lane == 0) {
        #pragma unroll
        for (int b = 0; b < NB; b++) red[wv][b] = acc[b];
    }
    __syncthreads();
    if (tid < NB) {
        float s = red[0][tid] + red[1][tid] + red[2][tid] + red[3][tid];
        logits[(size_t)tid * NCLS + o] = s + bc[o];
    }
}

// ---- Launch ----------------------------------------------------------------
extern "C" void kernel_launch(void* const* d_in, const int* in_sizes, int n_in,
                              void* d_out, int out_size, void* d_ws, size_t ws_size,
                              hipStream_t stream) {
    const float* x     = (const float*)d_in[0];
    const float* Wp    = (const float*)d_in[1];
    const float* bproj = (const float*)d_in[2];
    const float* qp    = (const float*)d_in[3];
    const float* kp    = (const float*)d_in[4];
    const float* vp    = (const float*)d_in[5];
    const float* Wc    = (const float*)d_in[6];
    const float* bc    = (const float*)d_in[7];
    float* logits = (float*)d_out;
    (void)d_ws; (void)ws_size;

    qcirc_kernel<<<dim3(NPATCH, NB, 3), 128, 0, stream>>>(x, Wp, bproj, qp, kp, vp);
    attn_kernel <<<dim3(NPATCH, NB),    256, 0, stream>>>(nullptr);
    cls_kernel  <<<NCLS,                256, 0, stream>>>(Wc, bc, logits);
}